// Round 5
// baseline (2195.795 us; speedup 1.0000x reference)
//
#include <hip/hip_runtime.h>

// ---------------------------------------------------------------------------
// ManualLSTM: B=32, S=512, H=1024.
//   Phase A: xg = bf16(x) @ bf16(Wi)  -> bf16 [16384][4096]  (bias in phase B)
//   Phase B (R11 = R10 + K-split waves + packed flags): persistent recurrence,
//     4 groups x 64 blocks. Group g owns batches 8g..8g+7 + full gate dim;
//     block m owns hidden cols m*16..+16 (64 gate cols).
//     - Wh B-frags pinned in VGPRs (asm "+v" tie; R10-validated). Reindexed
//       bfr[G*8+i]: wave wv owns K-range [wv*256, wv*256+256) for ALL 4 gate
//       groups (K-split) -> each wave reads only 8 A-frags from LDS (32
//       ds_read_b128/block/step, was 128; the 4 waves previously read the
//       SAME 16KB image 4x). 4 indep acc chains of depth 8.
//     - Partial sums reduced via gatesp[4][8][68] f32 in LDS (write-side
//       conflict-free layout); EW threads sum the 4 partials.
//     - Flags packed at 4B stride: the 64-flag poll is one coalesced 256B
//       load (4 lines, was 16).
//     - h exchange via NEVER-REUSED ring (512 slots x 4 groups x 16KB,
//       overlays dead xb region). Producers: shfl-packed 8B agent-scope
//       atomic stores. Consumers: PLAIN coalesced dwordx4 gather into LDS
//       (virgin addresses -> no stale L1/L2; R8/R9-validated).
//     - Drain: ring store first, out[] second, s_waitcnt vmcnt(1) waits the
//       ring store only; barrier; relaxed flag (R10-validated).
// ---------------------------------------------------------------------------

typedef __attribute__((ext_vector_type(4))) float f32x4_t;
typedef __attribute__((ext_vector_type(8))) short bf16x8_t;
typedef unsigned long long ull_t;

#define HID   1024
#define SLEN  512
#define NGATE 4096

// ws layout (bytes)
#define XG_OFF    0ULL                      // 16384*4096*2 = 134217728
#define RING_OFF  134217728ULL              // 512*4*16384  = 33554432 (old xb)
#define WIT_OFF   167772160ULL              // 4096*1024*2  = 8388608
#define WHT_OFF   176160768ULL              // 4096*1024*2  = 8388608
#define FLAGS_OFF 184680448ULL              // 256 packed 4B flags = 1024B
// xb (phase-A bf16 x) shares the RING region: gemm_xg reads it fully before
// lstm_persistent writes the ring (same stream, sequential dispatches).
#define XB_OFF    RING_OFF

#define NBLK_B      256                     // 4 groups x 64 blocks
#define SLOT_SHORTS 32768                   // 4 groups * 8192 shorts = 64KB/slot

__device__ __forceinline__ unsigned short f2bf(float f) {
  unsigned u = __float_as_uint(f);
  u += 0x7fffu + ((u >> 16) & 1u);          // round-nearest-even
  return (unsigned short)(u >> 16);
}
__device__ __forceinline__ float bf2f(unsigned short u) {
  return __uint_as_float(((unsigned)u) << 16);
}
__device__ __forceinline__ float fast_rcp(float x) { return __builtin_amdgcn_rcpf(x); }
__device__ __forceinline__ float sigmoid_f(float x) { return fast_rcp(1.f + __expf(-x)); }
__device__ __forceinline__ float tanh_f(float x) { return 1.f - 2.f * fast_rcp(1.f + __expf(2.f * x)); }

// ---------------------------------------------------------------- converters
__global__ __launch_bounds__(256) void conv_x_bf16(const float* __restrict__ in,
                                                   unsigned short* __restrict__ out) {
  size_t i = (size_t)blockIdx.x * 256 + threadIdx.x;
  const float4* p = (const float4*)in;
  float4 v = p[i];
  ushort4 o;
  o.x = f2bf(v.x); o.y = f2bf(v.y); o.z = f2bf(v.z); o.w = f2bf(v.w);
  ((ushort4*)out)[i] = o;
}

// in: fp32 [1024][4096]  -> out: bf16 [4096][1024]  (out[n][k] = in[k][n])
__global__ void transpose_w_bf16(const float* __restrict__ in,
                                 unsigned short* __restrict__ out) {
  __shared__ float tile[32][33];
  int tx = threadIdx.x, ty = threadIdx.y;        // block (32, 8)
  int n0 = blockIdx.x * 32, k0 = blockIdx.y * 32;
  #pragma unroll
  for (int i = 0; i < 4; i++)
    tile[ty + 8 * i][tx] = in[(size_t)(k0 + ty + 8 * i) * NGATE + n0 + tx];
  __syncthreads();
  #pragma unroll
  for (int i = 0; i < 4; i++)
    out[(size_t)(n0 + ty + 8 * i) * HID + k0 + tx] = f2bf(tile[tx][ty + 8 * i]);
}

__global__ void init_ws(unsigned* __restrict__ flags) {
  int i = threadIdx.x;                      // 256 packed flags
  flags[i] = 0u;
}

// ---------------------------------------------------------------- Phase A
// C[16384][4096] bf16 = A[16384][1024] bf16  x  BT[4096][1024] bf16
__global__ __launch_bounds__(256) void gemm_xg(const unsigned short* __restrict__ A,
                                               const unsigned short* __restrict__ BT,
                                               unsigned short* __restrict__ C) {
  extern __shared__ char smem[];
  char* As = smem;                 // 128 rows * 80B (32 bf16 + 16B pad)
  char* Bs = smem + 10240;
  const int tid = threadIdx.x;
  const int lane = tid & 63, w = tid >> 6, q = lane >> 4, l16 = lane & 15;
  const int wm = w & 1, wn = w >> 1;
  const size_t m0 = (size_t)blockIdx.y * 128, n0 = (size_t)blockIdx.x * 128;

  f32x4_t acc[4][4];
  #pragma unroll
  for (int i = 0; i < 4; i++)
    #pragma unroll
    for (int j = 0; j < 4; j++) acc[i][j] = (f32x4_t){0.f, 0.f, 0.f, 0.f};

  for (int kk = 0; kk < 32; kk++) {
    const int k0 = kk * 32;
    #pragma unroll
    for (int h = 0; h < 2; h++) {
      int idx = tid + h * 256;              // 0..511
      int r = idx >> 2, ch = idx & 3;
      uint4 va = *(const uint4*)((const char*)A + ((m0 + r) * HID + k0) * 2 + ch * 16);
      *(uint4*)(As + r * 80 + ch * 16) = va;
      uint4 vb = *(const uint4*)((const char*)BT + ((n0 + r) * HID + k0) * 2 + ch * 16);
      *(uint4*)(Bs + r * 80 + ch * 16) = vb;
    }
    __syncthreads();
    bf16x8_t af[4], bf[4];
    #pragma unroll
    for (int mt = 0; mt < 4; mt++)
      af[mt] = *(const bf16x8_t*)(As + (wm * 64 + mt * 16 + l16) * 80 + q * 16);
    #pragma unroll
    for (int nt = 0; nt < 4; nt++)
      bf[nt] = *(const bf16x8_t*)(Bs + (wn * 64 + nt * 16 + l16) * 80 + q * 16);
    #pragma unroll
    for (int mt = 0; mt < 4; mt++)
      #pragma unroll
      for (int nt = 0; nt < 4; nt++)
        acc[mt][nt] = __builtin_amdgcn_mfma_f32_16x16x32_bf16(af[mt], bf[nt], acc[mt][nt], 0, 0, 0);
    __syncthreads();
  }

  // epilogue: stage C tile (bf16 [128][136]) through LDS for coalesced stores
  unsigned short* cst = (unsigned short*)smem;
  #pragma unroll
  for (int mt = 0; mt < 4; mt++)
    #pragma unroll
    for (int nt = 0; nt < 4; nt++)
      #pragma unroll
      for (int r = 0; r < 4; r++) {
        int m = wm * 64 + mt * 16 + q * 4 + r;
        int n = wn * 64 + nt * 16 + l16;
        cst[m * 136 + n] = f2bf(acc[mt][nt][r]);
      }
  __syncthreads();
  #pragma unroll
  for (int i = 0; i < 8; i++) {
    int idx = tid + i * 256;                // < 2048
    int row = idx >> 4, ch = idx & 15;
    uint4 v = *(const uint4*)((const char*)cst + row * 272 + ch * 16);
    *(uint4*)((char*)C + ((m0 + row) * NGATE + n0) * 2 + ch * 16) = v;
  }
}

// ---------------------------------------------------------------- Phase B
// 4 groups x 64 blocks x 256 threads. Group = 8 batches, full gate dim.
// Block m: hidden cols m*16..+16 => local gate cols n = G*16+j, G=0..3.
// Wave wv: K-range [wv*256, wv*256+256), ALL 4 gate groups (K-split).
__global__ __launch_bounds__(256, 1) void lstm_persistent(
    const unsigned short* __restrict__ xg,   // [16384][4096] bf16
    const unsigned short* __restrict__ whT,  // [4096][1024] bf16
    const float* __restrict__ bias,          // [4096]
    float* __restrict__ out,                 // [32][512][1024]
    unsigned short* ring,                    // 512 slots x 4 groups x [8][1024] bf16
    unsigned* flags) {                       // 256 packed 4B, group-major
  __shared__ __align__(16) char h_lds[8 * 2064];   // [8 rows b][2048B k] +16B pad
  __shared__ float gatesp[4][8][68];               // [K-partial wv][b][4G*16 +pad]

  const int tid = threadIdx.x;
  const int lane = tid & 63, wv = tid >> 6, q = lane >> 4, l16 = lane & 15;
  const int g = blockIdx.x >> 6;                   // group 0..3
  const int m = blockIdx.x & 63;                   // member 0..63
  const int b_l = tid >> 4, j_l = tid & 15;        // EW mapping (tid<128)

  // pin Wh B-fragments in VGPRs: bfr[G*8+i] covers gate col block G, K-frag
  // kk = wv*8+i. Loaded once; volatile asm "+v" ties block the R8 failure
  // mode (compiler sinking the loads into the t-loop). R10-validated.
  bf16x8_t bfr[32];
  {
    #pragma unroll
    for (int G = 0; G < 4; G++) {
      const char* wrow = (const char*)whT +
          ((size_t)(G * 1024 + m * 16 + l16) * HID) * 2 + q * 16;
      #pragma unroll
      for (int i = 0; i < 8; i++)
        bfr[G * 8 + i] = *(const bf16x8_t*)(wrow + (wv * 8 + i) * 64);
    }
    #pragma unroll
    for (int kk = 0; kk < 32; kk++)
      asm volatile("" : "+v"(bfr[kk]));
  }
  float bsr[4];
  #pragma unroll
  for (int G = 0; G < 4; G++) bsr[G] = bias[G * 1024 + m * 16 + j_l];
  float c_st = 0.f;
  const char* arow = h_lds + (l16 & 7) * 2064 + q * 16;   // rows 8-15 mirror 0-7
  unsigned short* ring_g = ring + (size_t)g * 8192;       // 16KB group image
  unsigned* fl_g = flags + g * 64;                        // packed 4B flags

  for (int t = 0; t < SLEN; t++) {
    // xg prefetch (no h dependency) — overlaps the flag wait
    unsigned short xgv[4];
    if (tid < 128) {
      const unsigned short* p =
          xg + ((size_t)(g * 8 + b_l) * 512 + t) * 4096 + m * 16 + j_l;
      xgv[0] = p[0]; xgv[1] = p[1024]; xgv[2] = p[2048]; xgv[3] = p[3072];
    }
    if (t > 0) {
      if (tid < 64) {
        const unsigned* fp = fl_g + tid;     // 64 lanes = one 256B load
        while (__hip_atomic_load(fp, __ATOMIC_RELAXED, __HIP_MEMORY_SCOPE_AGENT) < (unsigned)t)
          __builtin_amdgcn_s_sleep(1);
      }
      __syncthreads();
      asm volatile("" ::: "memory");
      // gather group h image from ring slot t-1 with PLAIN coalesced dwordx4
      // (virgin addresses -> no stale L1/L2; producers wrote LLC; lane-
      //  contiguous 16B chunks -> 1KB/instruction, line-based, L2-shared)
      {
        const char* src = (const char*)(ring_g + (size_t)(t - 1) * SLOT_SHORTS);
        uint4 v0 = *(const uint4*)(src + tid * 16);
        uint4 v1 = *(const uint4*)(src + tid * 16 + 4096);
        uint4 v2 = *(const uint4*)(src + tid * 16 + 8192);
        uint4 v3 = *(const uint4*)(src + tid * 16 + 12288);
        int c0 = tid, c1 = tid + 256, c2 = tid + 512, c3 = tid + 768;
        *(uint4*)(h_lds + (c0 >> 7) * 2064 + (c0 & 127) * 16) = v0;
        *(uint4*)(h_lds + (c1 >> 7) * 2064 + (c1 & 127) * 16) = v1;
        *(uint4*)(h_lds + (c2 >> 7) * 2064 + (c2 & 127) * 16) = v2;
        *(uint4*)(h_lds + (c3 >> 7) * 2064 + (c3 & 127) * 16) = v3;
      }
    }
    __syncthreads();

    // K-split MFMA: wave wv reads only its 8 A-frags (kk = wv*8+i) and
    // accumulates partials for all 4 gate groups (4 indep chains, depth 8).
    f32x4_t acc[4];
    #pragma unroll
    for (int G = 0; G < 4; G++) acc[G] = (f32x4_t){0.f, 0.f, 0.f, 0.f};
    if (t > 0) {
      #pragma unroll
      for (int i = 0; i < 8; i++) {
        bf16x8_t a = *(const bf16x8_t*)(arow + (wv * 8 + i) * 64);
        acc[0] = __builtin_amdgcn_mfma_f32_16x16x32_bf16(a, bfr[0 * 8 + i], acc[0], 0, 0, 0);
        acc[1] = __builtin_amdgcn_mfma_f32_16x16x32_bf16(a, bfr[1 * 8 + i], acc[1], 0, 0, 0);
        acc[2] = __builtin_amdgcn_mfma_f32_16x16x32_bf16(a, bfr[2 * 8 + i], acc[2], 0, 0, 0);
        acc[3] = __builtin_amdgcn_mfma_f32_16x16x32_bf16(a, bfr[3 * 8 + i], acc[3], 0, 0, 0);
      }
    }
    // store partials: rows 0..7 only (q<2); rows 8-15 are mirror duplicates.
    // Write banks: two 16-lane runs offset by 16 -> conflict-free.
    if (q < 2) {
      #pragma unroll
      for (int G = 0; G < 4; G++)
        #pragma unroll
        for (int r = 0; r < 4; r++)
          gatesp[wv][q * 4 + r][G * 16 + l16] = acc[G][r];
    }
    __syncthreads();

    // elementwise: 128 threads own (b_l, j_l); sum the 4 K-partials
    if (tid < 128) {
      float gi = gatesp[0][b_l][j_l]      + gatesp[1][b_l][j_l]
               + gatesp[2][b_l][j_l]      + gatesp[3][b_l][j_l]
               + bsr[0] + bf2f(xgv[0]);
      float gf = gatesp[0][b_l][16 + j_l] + gatesp[1][b_l][16 + j_l]
               + gatesp[2][b_l][16 + j_l] + gatesp[3][b_l][16 + j_l]
               + bsr[1] + bf2f(xgv[1]);
      float gg = gatesp[0][b_l][32 + j_l] + gatesp[1][b_l][32 + j_l]
               + gatesp[2][b_l][32 + j_l] + gatesp[3][b_l][32 + j_l]
               + bsr[2] + bf2f(xgv[2]);
      float go = gatesp[0][b_l][48 + j_l] + gatesp[1][b_l][48 + j_l]
               + gatesp[2][b_l][48 + j_l] + gatesp[3][b_l][48 + j_l]
               + bsr[3] + bf2f(xgv[3]);
      float i_s = sigmoid_f(gi), f_s = sigmoid_f(gf);
      float g_t = tanh_f(gg), o_s = sigmoid_f(go);
      c_st = f_s * c_st + i_s * g_t;
      float h = o_s * tanh_f(c_st);
      // pack 4 cols into 8B via two shuffles; lanes j%4==0 store LLC-direct.
      // Ring store issued FIRST (oldest) so vmcnt(1) below waits only it.
      unsigned short hb = f2bf(h);
      unsigned other = __shfl_xor((unsigned)hb, 1);
      unsigned u = ((unsigned)hb & 0xffffu) | (other << 16);   // cols j, j+1
      unsigned u2 = __shfl_xor(u, 2);                          // cols j+2, j+3
      if ((j_l & 3) == 0) {
        ull_t v8 = (ull_t)u | ((ull_t)u2 << 32);
        ull_t* dst = (ull_t*)(ring_g + (size_t)t * SLOT_SHORTS +
                              b_l * 1024 + m * 16 + j_l);
        __hip_atomic_store(dst, v8, __ATOMIC_RELAXED, __HIP_MEMORY_SCOPE_AGENT);
      }
      asm volatile("" ::: "memory");   // keep out-store AFTER ring store
      out[((size_t)(g * 8 + b_l) * 512 + t) * 1024 + m * 16 + j_l] = h;
    }
    // drain the ring store only (oldest); out[] HBM ack stays off the path
    asm volatile("s_waitcnt vmcnt(1)" ::: "memory");
    __syncthreads();
    if (tid == 0)
      __hip_atomic_store(fl_g + m, (unsigned)(t + 1),
                         __ATOMIC_RELAXED, __HIP_MEMORY_SCOPE_AGENT);
  }
}

// ---------------------------------------------------------------- launcher
extern "C" void kernel_launch(void* const* d_in, const int* in_sizes, int n_in,
                              void* d_out, int out_size, void* d_ws, size_t ws_size,
                              hipStream_t stream) {
  const float* x    = (const float*)d_in[0];   // [32,512,1024]
  const float* wi   = (const float*)d_in[1];   // [1024,4096]
  const float* wh   = (const float*)d_in[2];   // [1024,4096]
  const float* bias = (const float*)d_in[3];   // [4096]
  float* out = (float*)d_out;

  char* ws = (char*)d_ws;
  unsigned short* xg   = (unsigned short*)(ws + XG_OFF);
  unsigned short* xb   = (unsigned short*)(ws + XB_OFF);   // dead after gemm_xg
  unsigned short* ring = (unsigned short*)(ws + RING_OFF); // overlays xb
  unsigned short* wiT  = (unsigned short*)(ws + WIT_OFF);
  unsigned short* whT  = (unsigned short*)(ws + WHT_OFF);
  unsigned* flags      = (unsigned*)(ws + FLAGS_OFF);

  conv_x_bf16<<<16384, 256, 0, stream>>>(x, xb);
  transpose_w_bf16<<<dim3(128, 32), dim3(32, 8), 0, stream>>>(wi, wiT);
  transpose_w_bf16<<<dim3(128, 32), dim3(32, 8), 0, stream>>>(wh, whT);
  init_ws<<<1, 256, 0, stream>>>(flags);
  gemm_xg<<<dim3(32, 128), 256, 34816, stream>>>(xb, wiT, xg);
  lstm_persistent<<<NBLK_B, 256, 0, stream>>>(xg, whT, bias, out, ring, flags);
}